// Round 2
// baseline (697.080 us; speedup 1.0000x reference)
//
#include <hip/hip_runtime.h>
#include <stdint.h>
#include <math.h>

typedef __attribute__((ext_vector_type(8))) short short8;
typedef __attribute__((ext_vector_type(4))) float f32x4;

struct alignas(8) U16x4 { unsigned short x, y, z, w; };

#define S_LEN 2048
#define NBATCH 32
#define KDIM 1024
#define MROWS 65536
#define NEG_INF_F (-1e9f)

#define BM 128
#define BN 256
#define BK 32
#define LDT 40  /* fallback path: padded LDS row stride in ushorts */

__device__ __forceinline__ void split2(float x, unsigned short& h, unsigned short& l) {
    union { float f; uint32_t u; } a; a.f = x;
    h = (unsigned short)(a.u >> 16);
    union { float f; uint32_t u; } hf; hf.u = a.u & 0xFFFF0000u;
    union { float f; uint32_t u; } lf; lf.f = x - hf.f;
    l = (unsigned short)(lf.u >> 16);
}

__device__ __forceinline__ void gload_lds16(const unsigned short* g, unsigned short* l) {
    __builtin_amdgcn_global_load_lds(
        (const __attribute__((address_space(1))) void*)g,
        (__attribute__((address_space(3))) void*)l, 16, 0, 0);
}

// ---------------------------------------------------------------------------
// dec[b,e] = sum_d dh[b,d] * Ws[e,d]   (one block per e)
// ---------------------------------------------------------------------------
__global__ __launch_bounds__(256) void dec_kernel(
    const float* __restrict__ dh, const float* __restrict__ Ws,
    float* __restrict__ dec)
{
    __shared__ float wrow[1024];
    int e = blockIdx.x;
    int t = threadIdx.x;
    #pragma unroll
    for (int i = t; i < 1024; i += 256) wrow[i] = Ws[(size_t)e * 1024 + i];
    __syncthreads();
    int b = t >> 3, part = t & 7;
    const float* dhp = dh + (size_t)b * 1024 + part * 128;
    const float* wp  = wrow + part * 128;
    float s = 0.f;
    #pragma unroll 8
    for (int i = 0; i < 128; ++i) s += dhp[i] * wp[i];
    s += __shfl_xor(s, 1);
    s += __shfl_xor(s, 2);
    s += __shfl_xor(s, 4);
    if (part == 0) dec[(size_t)b * 1024 + e] = s;
}

// ---------------------------------------------------------------------------
// Pre-pass: split f32 matrix [n_msub*16, 1024] into hi/lo bf16, stored in
// MFMA-fragment-lane order per 16x32 subtile:
//   out[(ks*n_msub + ms)*512 + lane*8 + j] =
//       src[(ms*16 + (lane&15))*1024 + ks*32 + (lane>>4)*8 + j]
// One wave per subtile; 4 waves per block.
// ---------------------------------------------------------------------------
__global__ __launch_bounds__(256) void convert_split(
    const float* __restrict__ src, unsigned short* __restrict__ hi,
    unsigned short* __restrict__ lo, int lg_nmsub)
{
    int gid = blockIdx.x * 4 + (threadIdx.x >> 6);
    int lane = threadIdx.x & 63;
    int ms = gid & ((1 << lg_nmsub) - 1);
    int ks = gid >> lg_nmsub;
    const float* p = src + ((size_t)(ms * 16 + (lane & 15))) * 1024
                         + ks * 32 + (lane >> 4) * 8;
    f32x4 a = *(const f32x4*)p;
    f32x4 b = *(const f32x4*)(p + 4);
    union { unsigned short u[8]; short8 v; } h, l;
    split2(a.x, h.u[0], l.u[0]); split2(a.y, h.u[1], l.u[1]);
    split2(a.z, h.u[2], l.u[2]); split2(a.w, h.u[3], l.u[3]);
    split2(b.x, h.u[4], l.u[4]); split2(b.y, h.u[5], l.u[5]);
    split2(b.z, h.u[6], l.u[6]); split2(b.w, h.u[7], l.u[7]);
    size_t o = (size_t)gid * 512 + lane * 8;
    *(short8*)(hi + o) = h.v;
    *(short8*)(lo + o) = l.v;
}

// ---------------------------------------------------------------------------
// Fast energy GEMM: pre-split bf16 inputs in fragment order, global_load_lds
// staging, linear conflict-free LDS, 3-pass split-precision MFMA.
// Grid: 2048 blocks (512 M x 4 N), 512 threads (8 waves, 2x4 of 64x64 tiles).
// ---------------------------------------------------------------------------
__global__ __launch_bounds__(512) void energy_gemm_v2(
    const unsigned short* __restrict__ Ahi, const unsigned short* __restrict__ Alo,
    const unsigned short* __restrict__ Bhi, const unsigned short* __restrict__ Blo,
    const float* __restrict__ dec, const float* __restrict__ v,
    float* __restrict__ energy)
{
    // 48 KB: A_hi[8 subtiles], A_lo[8], B_hi[16], B_lo[16], each subtile 1 KB
    __shared__ unsigned short lds[24576];

    int bid = blockIdx.x;
    int lid = (bid & 7) * 256 + (bid >> 3);   // XCD swizzle: 4 N-blocks of an
    int mblk = lid >> 2, nblk = lid & 3;      // M-block land on one XCD
    int m0 = mblk * BM, n0 = nblk * BN;
    int b = m0 / S_LEN;

    int t = threadIdx.x, wid = t >> 6, lane = t & 63;
    int wm = wid >> 2, wn = wid & 3;
    int kg = lane >> 4, lr = lane & 15;

    f32x4 acc[4][4] = {};
    int c0 = wid * 6;                 // 48 chunks of 1 KB, 6 per wave

    for (int ks = 0; ks < 32; ++ks) {
        int abase = ks * 4096 + mblk * 8;
        int bbase = ks * 64 + nblk * 16;
        #pragma unroll
        for (int i = 0; i < 6; ++i) {
            int c = c0 + i;
            const unsigned short* g;
            if (c < 8)       g = Ahi + (size_t)(abase + c) * 512;
            else if (c < 16) g = Alo + (size_t)(abase + (c - 8)) * 512;
            else if (c < 32) g = Bhi + (size_t)(bbase + (c - 16)) * 512;
            else             g = Blo + (size_t)(bbase + (c - 32)) * 512;
            gload_lds16(g + lane * 8, &lds[c * 512]);
        }
        __syncthreads();   // drains vmcnt; staged data visible

        short8 afh[4], afl[4], bfh[4], bfl[4];
        #pragma unroll
        for (int mi = 0; mi < 4; ++mi) {
            int s = (wm * 4 + mi) * 512 + lane * 8;
            afh[mi] = *(const short8*)&lds[s];
            afl[mi] = *(const short8*)&lds[4096 + s];
        }
        #pragma unroll
        for (int ni = 0; ni < 4; ++ni) {
            int s = (wn * 4 + ni) * 512 + lane * 8;
            bfh[ni] = *(const short8*)&lds[8192 + s];
            bfl[ni] = *(const short8*)&lds[16384 + s];
        }
        #pragma unroll
        for (int mi = 0; mi < 4; ++mi)
            #pragma unroll
            for (int ni = 0; ni < 4; ++ni) {
                acc[mi][ni] = __builtin_amdgcn_mfma_f32_16x16x32_bf16(afh[mi], bfh[ni], acc[mi][ni], 0, 0, 0);
                acc[mi][ni] = __builtin_amdgcn_mfma_f32_16x16x32_bf16(afl[mi], bfh[ni], acc[mi][ni], 0, 0, 0);
                acc[mi][ni] = __builtin_amdgcn_mfma_f32_16x16x32_bf16(afh[mi], bfl[ni], acc[mi][ni], 0, 0, 0);
            }
        __syncthreads();
    }

    // ---- epilogue: energy[m] += sum_n tanh(enc + dec) * v
    float vv[4], dd[4];
    #pragma unroll
    for (int ni = 0; ni < 4; ++ni) {
        int d = n0 + wn * 64 + ni * 16 + lr;
        vv[ni] = v[d];
        dd[ni] = dec[(size_t)b * 1024 + d];
    }
    #pragma unroll
    for (int mi = 0; mi < 4; ++mi) {
        #pragma unroll
        for (int r = 0; r < 4; ++r) {
            float local = 0.f;
            #pragma unroll
            for (int ni = 0; ni < 4; ++ni)
                local += tanhf(acc[mi][ni][r] + dd[ni]) * vv[ni];
            local += __shfl_xor(local, 1);
            local += __shfl_xor(local, 2);
            local += __shfl_xor(local, 4);
            local += __shfl_xor(local, 8);
            if (lr == 0) {
                int m = m0 + wm * 64 + mi * 16 + kg * 4 + r;
                atomicAdd(&energy[m], local);
            }
        }
    }
}

// ---------------------------------------------------------------------------
// Fallback fused GEMM (round-1 kernel) used when ws_size is too small for the
// pre-converted buffers.
// ---------------------------------------------------------------------------
__global__ __launch_bounds__(512) void energy_gemm_fused(
    const float* __restrict__ A, const float* __restrict__ Wh,
    const float* __restrict__ dec, const float* __restrict__ v,
    float* __restrict__ energy)
{
    __shared__ unsigned short As_hi[BM * LDT];
    __shared__ unsigned short As_lo[BM * LDT];
    __shared__ unsigned short Bs_hi[BN * LDT];
    __shared__ unsigned short Bs_lo[BN * LDT];

    int bid = blockIdx.x;
    int lid = (bid & 7) * 256 + (bid >> 3);
    int mblk = lid >> 2, nblk = lid & 3;
    int m0 = mblk * BM, n0 = nblk * BN;
    int b = m0 / S_LEN;

    int t = threadIdx.x;
    int wid = t >> 6, lane = t & 63;
    int wm = wid >> 2, wn = wid & 3;
    int kg = lane >> 4, lr = lane & 15;

    f32x4 acc[4][4] = {};

    for (int k0 = 0; k0 < KDIM; k0 += BK) {
        #pragma unroll
        for (int p = 0; p < 2; ++p) {
            int idx = t + p * 512;
            int row = idx >> 3, cg = idx & 7;
            f32x4 xv = *(const f32x4*)(A + (size_t)(m0 + row) * KDIM + k0 + cg * 4);
            U16x4 h, l;
            split2(xv.x, h.x, l.x); split2(xv.y, h.y, l.y);
            split2(xv.z, h.z, l.z); split2(xv.w, h.w, l.w);
            *(U16x4*)&As_hi[row * LDT + cg * 4] = h;
            *(U16x4*)&As_lo[row * LDT + cg * 4] = l;
        }
        #pragma unroll
        for (int p = 0; p < 4; ++p) {
            int idx = t + p * 512;
            int row = idx >> 3, cg = idx & 7;
            f32x4 xv = *(const f32x4*)(Wh + (size_t)(n0 + row) * KDIM + k0 + cg * 4);
            U16x4 h, l;
            split2(xv.x, h.x, l.x); split2(xv.y, h.y, l.y);
            split2(xv.z, h.z, l.z); split2(xv.w, h.w, l.w);
            *(U16x4*)&Bs_hi[row * LDT + cg * 4] = h;
            *(U16x4*)&Bs_lo[row * LDT + cg * 4] = l;
        }
        __syncthreads();

        short8 afh[4], afl[4], bfh[4], bfl[4];
        #pragma unroll
        for (int mi = 0; mi < 4; ++mi) {
            int off = (wm * 64 + mi * 16 + lr) * LDT + kg * 8;
            afh[mi] = *(const short8*)&As_hi[off];
            afl[mi] = *(const short8*)&As_lo[off];
        }
        #pragma unroll
        for (int ni = 0; ni < 4; ++ni) {
            int off = (wn * 64 + ni * 16 + lr) * LDT + kg * 8;
            bfh[ni] = *(const short8*)&Bs_hi[off];
            bfl[ni] = *(const short8*)&Bs_lo[off];
        }
        #pragma unroll
        for (int mi = 0; mi < 4; ++mi)
            #pragma unroll
            for (int ni = 0; ni < 4; ++ni) {
                acc[mi][ni] = __builtin_amdgcn_mfma_f32_16x16x32_bf16(afh[mi], bfh[ni], acc[mi][ni], 0, 0, 0);
                acc[mi][ni] = __builtin_amdgcn_mfma_f32_16x16x32_bf16(afl[mi], bfh[ni], acc[mi][ni], 0, 0, 0);
                acc[mi][ni] = __builtin_amdgcn_mfma_f32_16x16x32_bf16(afh[mi], bfl[ni], acc[mi][ni], 0, 0, 0);
            }
        __syncthreads();
    }

    float vv[4], dd[4];
    #pragma unroll
    for (int ni = 0; ni < 4; ++ni) {
        int d = n0 + wn * 64 + ni * 16 + lr;
        vv[ni] = v[d];
        dd[ni] = dec[(size_t)b * 1024 + d];
    }
    #pragma unroll
    for (int mi = 0; mi < 4; ++mi) {
        #pragma unroll
        for (int r = 0; r < 4; ++r) {
            float local = 0.f;
            #pragma unroll
            for (int ni = 0; ni < 4; ++ni)
                local += tanhf(acc[mi][ni][r] + dd[ni]) * vv[ni];
            local += __shfl_xor(local, 1);
            local += __shfl_xor(local, 2);
            local += __shfl_xor(local, 4);
            local += __shfl_xor(local, 8);
            if (lr == 0) {
                int m = m0 + wm * 64 + mi * 16 + kg * 4 + r;
                atomicAdd(&energy[m], local);
            }
        }
    }
}

// ---------------------------------------------------------------------------
// Masked softmax over S per batch row. One block per b.
// ---------------------------------------------------------------------------
__global__ __launch_bounds__(256) void softmax_kernel(
    const float* __restrict__ energy, const int* __restrict__ mask,
    float* __restrict__ attn)
{
    int b = blockIdx.x;
    int t = threadIdx.x;
    int wid = t >> 6, lane = t & 63;
    __shared__ float wmax[4], wsum[4];

    float vals[8];
    float mx = -INFINITY;
    #pragma unroll
    for (int j = 0; j < 8; ++j) {
        int s = t + j * 256;
        float e = energy[(size_t)b * S_LEN + s];
        if (mask[(size_t)b * S_LEN + s] == 0) e = NEG_INF_F;
        vals[j] = e;
        mx = fmaxf(mx, e);
    }
    #pragma unroll
    for (int m = 1; m < 64; m <<= 1) mx = fmaxf(mx, __shfl_xor(mx, m));
    if (lane == 0) wmax[wid] = mx;
    __syncthreads();
    mx = fmaxf(fmaxf(wmax[0], wmax[1]), fmaxf(wmax[2], wmax[3]));

    float sum = 0.f;
    #pragma unroll
    for (int j = 0; j < 8; ++j) { vals[j] = expf(vals[j] - mx); sum += vals[j]; }
    #pragma unroll
    for (int m = 1; m < 64; m <<= 1) sum += __shfl_xor(sum, m);
    if (lane == 0) wsum[wid] = sum;
    __syncthreads();
    sum = wsum[0] + wsum[1] + wsum[2] + wsum[3];
    float inv = 1.f / sum;
    #pragma unroll
    for (int j = 0; j < 8; ++j)
        attn[(size_t)b * S_LEN + t + j * 256] = vals[j] * inv;
}

// ---------------------------------------------------------------------------
// context[b,e] = sum_s attn[b,s] * x[b,s,e]. Grid (4 e-chunks, 32 b, 16 s-chunks).
// ---------------------------------------------------------------------------
__global__ __launch_bounds__(256) void context_kernel(
    const float* __restrict__ attn, const float* __restrict__ x,
    float* __restrict__ ctx)
{
    int ec = blockIdx.x, b = blockIdx.y, sc = blockIdx.z;
    int e = ec * 256 + threadIdx.x;
    const float* xp = x + ((size_t)b * S_LEN + sc * 128) * KDIM + e;
    const float* ap = attn + (size_t)b * S_LEN + sc * 128;
    float acc = 0.f;
    #pragma unroll 4
    for (int s = 0; s < 128; ++s) acc += ap[s] * xp[(size_t)s * KDIM];
    atomicAdd(&ctx[(size_t)b * KDIM + e], acc);
}

// ---------------------------------------------------------------------------
extern "C" void kernel_launch(void* const* d_in, const int* in_sizes, int n_in,
                              void* d_out, int out_size, void* d_ws, size_t ws_size,
                              hipStream_t stream) {
    const float* dh   = (const float*)d_in[0];  // [32,1024]
    const float* x    = (const float*)d_in[1];  // [32,2048,1024]
    const int*   mask = (const int*)d_in[2];    // [32,2048]
    const float* Wh   = (const float*)d_in[3];  // [1024,1024]
    const float* Ws   = (const float*)d_in[4];  // [1024,1024]
    const float* v    = (const float*)d_in[5];  // [1024]

    float* ctx  = (float*)d_out;                 // [32*1024]
    float* attn = (float*)d_out + 32 * 1024;     // [32*2048]

    const size_t NEED = 2ull * 134217728 + 2ull * 2097152 + 131072 + 262144;

    if (ws_size >= NEED) {
        unsigned short* Ahi = (unsigned short*)d_ws;       // 67108864 el
        unsigned short* Alo = Ahi + 67108864ull;           // 67108864 el
        unsigned short* Bhi = Alo + 67108864ull;           // 1048576 el
        unsigned short* Blo = Bhi + 1048576ull;            // 1048576 el
        float* dec    = (float*)(Blo + 1048576ull);        // 32768 f32
        float* energy = dec + 32768;                       // 65536 f32

        hipMemsetAsync(energy, 0, 65536 * sizeof(float), stream);
        hipMemsetAsync(ctx, 0, 32768 * sizeof(float), stream);

        dec_kernel<<<1024, 256, 0, stream>>>(dh, Ws, dec);
        convert_split<<<32768, 256, 0, stream>>>(x, Ahi, Alo, 12);   // 4096 msubs
        convert_split<<<512, 256, 0, stream>>>(Wh, Bhi, Blo, 6);     // 64 msubs
        energy_gemm_v2<<<2048, 512, 0, stream>>>(Ahi, Alo, Bhi, Blo, dec, v, energy);
        softmax_kernel<<<NBATCH, 256, 0, stream>>>(energy, mask, attn);
        context_kernel<<<dim3(4, NBATCH, 16), 256, 0, stream>>>(attn, x, ctx);
    } else {
        float* dec    = (float*)d_ws;
        float* energy = dec + 32768;

        hipMemsetAsync(energy, 0, 65536 * sizeof(float), stream);
        hipMemsetAsync(ctx, 0, 32768 * sizeof(float), stream);

        dec_kernel<<<1024, 256, 0, stream>>>(dh, Ws, dec);
        energy_gemm_fused<<<2048, 512, 0, stream>>>(x, Wh, dec, v, energy);
        softmax_kernel<<<NBATCH, 256, 0, stream>>>(energy, mask, attn);
        context_kernel<<<dim3(4, NBATCH, 16), 256, 0, stream>>>(attn, x, ctx);
    }
}

// Round 3
// 422.595 us; speedup vs baseline: 1.6495x; 1.6495x over previous
//
#include <hip/hip_runtime.h>
#include <stdint.h>
#include <math.h>

typedef __attribute__((ext_vector_type(8))) short short8;
typedef __attribute__((ext_vector_type(4))) float f32x4;

#define S_LEN 2048
#define NBATCH 32
#define KDIM 1024
#define NEG_INF_F (-1e9f)

#define BM 128
#define BN 128
#define BK 32

__device__ __forceinline__ void split2(float x, unsigned short& h, unsigned short& l) {
    union { float f; uint32_t u; } a; a.f = x;
    h = (unsigned short)(a.u >> 16);
    union { float f; uint32_t u; } hf; hf.u = a.u & 0xFFFF0000u;
    union { float f; uint32_t u; } lf; lf.f = x - hf.f;
    l = (unsigned short)(lf.u >> 16);
}

// round-half-up f32 -> bf16, two at a time, packed into one dword
__device__ __forceinline__ uint32_t pack_bf16hi(float f0, float f1) {
    union { float f; uint32_t u; } a, b; a.f = f0; b.f = f1;
    return ((a.u + 0x8000u) >> 16) | ((b.u + 0x8000u) & 0xFFFF0000u);
}

__device__ __forceinline__ void gload_lds16(const unsigned short* g, unsigned short* l) {
    __builtin_amdgcn_global_load_lds(
        (const __attribute__((address_space(1))) void*)g,
        (__attribute__((address_space(3))) void*)l, 16, 0, 0);
}

// ---------------------------------------------------------------------------
// dec[b,e] = sum_d dh[b,d] * Ws[e,d]   (one block per e)
// ---------------------------------------------------------------------------
__global__ __launch_bounds__(256) void dec_kernel(
    const float* __restrict__ dh, const float* __restrict__ Ws,
    float* __restrict__ dec)
{
    __shared__ float wrow[1024];
    int e = blockIdx.x;
    int t = threadIdx.x;
    #pragma unroll
    for (int i = t; i < 1024; i += 256) wrow[i] = Ws[(size_t)e * 1024 + i];
    __syncthreads();
    int b = t >> 3, part = t & 7;
    const float* dhp = dh + (size_t)b * 1024 + part * 128;
    const float* wp  = wrow + part * 128;
    float s = 0.f;
    #pragma unroll 8
    for (int i = 0; i < 128; ++i) s += dhp[i] * wp[i];
    s += __shfl_xor(s, 1);
    s += __shfl_xor(s, 2);
    s += __shfl_xor(s, 4);
    if (part == 0) dec[(size_t)b * 1024 + e] = s;
}

// ---------------------------------------------------------------------------
// Pre-pass for B (Wh) only: split f32 [64*16,1024] -> hi/lo bf16 in
// MFMA-fragment-lane order per 16x32 subtile. gid = ks*64 + msub.
// ---------------------------------------------------------------------------
__global__ __launch_bounds__(256) void convert_split(
    const float* __restrict__ src, unsigned short* __restrict__ hi,
    unsigned short* __restrict__ lo, int lg_nmsub)
{
    int gid = blockIdx.x * 4 + (threadIdx.x >> 6);
    int lane = threadIdx.x & 63;
    int ms = gid & ((1 << lg_nmsub) - 1);
    int ks = gid >> lg_nmsub;
    const float* p = src + ((size_t)(ms * 16 + (lane & 15))) * 1024
                         + ks * 32 + (lane >> 4) * 8;
    f32x4 a = *(const f32x4*)p;
    f32x4 b = *(const f32x4*)(p + 4);
    union { unsigned short u[8]; short8 v; } h, l;
    split2(a.x, h.u[0], l.u[0]); split2(a.y, h.u[1], l.u[1]);
    split2(a.z, h.u[2], l.u[2]); split2(a.w, h.u[3], l.u[3]);
    split2(b.x, h.u[4], l.u[4]); split2(b.y, h.u[5], l.u[5]);
    split2(b.z, h.u[6], l.u[6]); split2(b.w, h.u[7], l.u[7]);
    size_t o = (size_t)gid * 512 + lane * 8;
    *(short8*)(hi + o) = h.v;
    *(short8*)(lo + o) = l.v;
}

// ---------------------------------------------------------------------------
// energy GEMM v3: A (encoder_outputs, f32) converted to bf16-hi in-register
// during LDS staging; B pre-split hi/lo staged via global_load_lds.
// 2-pass split precision: enc ~= Ah*Bh + Ah*Bl, fp32 accum.
// Tile 128x128, 256 threads (2x2 waves of 64x64), 4 blocks/CU target.
// Grid: 4096 blocks = 512 M-blocks x 8 N-blocks, XCD-swizzled.
// ---------------------------------------------------------------------------
__global__ __launch_bounds__(256, 4) void energy_gemm_v3(
    const float* __restrict__ x,           // [65536,1024] f32
    const unsigned short* __restrict__ Bhi,
    const unsigned short* __restrict__ Blo,
    const float* __restrict__ dec, const float* __restrict__ v,
    float* __restrict__ energy)
{
    // 24 KB: A_hi 8 subtiles | B_hi 8 | B_lo 8  (subtile = 512 ushorts = 1 KB)
    __shared__ unsigned short lds[12288];

    int bid = blockIdx.x;
    int lid = (bid & 7) * 512 + (bid >> 3);  // 8 N-blocks of an M-block -> same XCD
    int mblk = lid >> 3, nblk = lid & 7;
    int m0 = mblk * BM, n0 = nblk * BN;
    int b = mblk >> 4;                        // BM=128, S=2048 -> 16 mblks per batch

    int t = threadIdx.x, wid = t >> 6, lane = t & 63;
    int wm = wid >> 1, wn = wid & 1;
    int kg = lane >> 4, lr = lane & 15;

    f32x4 acc[4][4] = {};

    for (int ks = 0; ks < 32; ++ks) {
        // ---- stage B: 16 x 1KB chunks via global_load_lds (4 per wave)
        int bbase = ks * 64 + nblk * 8;
        #pragma unroll
        for (int i = 0; i < 4; ++i) {
            int c = wid * 4 + i;
            const unsigned short* g = (c < 8)
                ? Bhi + (size_t)(bbase + c) * 512
                : Blo + (size_t)(bbase + (c - 8)) * 512;
            gload_lds16(g + lane * 8, &lds[4096 + c * 512]);
        }
        // ---- stage A: reg-load f32, convert to bf16-hi, ds_write in frag order
        int acol = ks * 32;
        #pragma unroll
        for (int p = 0; p < 2; ++p) {
            int idx = p * 256 + t;
            int ms = idx >> 6, ln = idx & 63;
            const float* ap = x + (size_t)(m0 + ms * 16 + (ln & 15)) * KDIM
                                + acol + (ln >> 4) * 8;
            f32x4 a0 = *(const f32x4*)ap;
            f32x4 a1 = *(const f32x4*)(ap + 4);
            union { uint32_t d[4]; short8 v; } o;
            o.d[0] = pack_bf16hi(a0.x, a0.y);
            o.d[1] = pack_bf16hi(a0.z, a0.w);
            o.d[2] = pack_bf16hi(a1.x, a1.y);
            o.d[3] = pack_bf16hi(a1.z, a1.w);
            *(short8*)&lds[ms * 512 + ln * 8] = o.v;
        }
        __syncthreads();   // drains vmcnt (gload_lds) + lgkmcnt (ds_write)

        // ---- fragments + MFMA (keep live regs low: B frags preloaded, A per-mi)
        short8 bfh[4], bfl[4];
        #pragma unroll
        for (int ni = 0; ni < 4; ++ni) {
            int s = (wn * 4 + ni) * 512 + lane * 8;
            bfh[ni] = *(const short8*)&lds[4096 + s];
            bfl[ni] = *(const short8*)&lds[8192 + s];
        }
        #pragma unroll
        for (int mi = 0; mi < 4; ++mi) {
            short8 afh = *(const short8*)&lds[(wm * 4 + mi) * 512 + lane * 8];
            #pragma unroll
            for (int ni = 0; ni < 4; ++ni) {
                acc[mi][ni] = __builtin_amdgcn_mfma_f32_16x16x32_bf16(afh, bfh[ni], acc[mi][ni], 0, 0, 0);
                acc[mi][ni] = __builtin_amdgcn_mfma_f32_16x16x32_bf16(afh, bfl[ni], acc[mi][ni], 0, 0, 0);
            }
        }
        __syncthreads();
    }

    // ---- epilogue: energy[m] += sum_n tanh(enc + dec) * v
    float vv[4], dd[4];
    #pragma unroll
    for (int ni = 0; ni < 4; ++ni) {
        int d = n0 + wn * 64 + ni * 16 + lr;
        vv[ni] = v[d];
        dd[ni] = dec[(size_t)b * 1024 + d];
    }
    #pragma unroll
    for (int mi = 0; mi < 4; ++mi) {
        #pragma unroll
        for (int r = 0; r < 4; ++r) {
            float local = 0.f;
            #pragma unroll
            for (int ni = 0; ni < 4; ++ni)
                local += tanhf(acc[mi][ni][r] + dd[ni]) * vv[ni];
            local += __shfl_xor(local, 1);
            local += __shfl_xor(local, 2);
            local += __shfl_xor(local, 4);
            local += __shfl_xor(local, 8);
            if (lr == 0) {
                int m = m0 + wm * 64 + mi * 16 + kg * 4 + r;
                atomicAdd(&energy[m], local);
            }
        }
    }
}

// ---------------------------------------------------------------------------
// Masked softmax over S per batch row. One block per b.
// ---------------------------------------------------------------------------
__global__ __launch_bounds__(256) void softmax_kernel(
    const float* __restrict__ energy, const int* __restrict__ mask,
    float* __restrict__ attn)
{
    int b = blockIdx.x;
    int t = threadIdx.x;
    int wid = t >> 6, lane = t & 63;
    __shared__ float wmax[4], wsum[4];

    float vals[8];
    float mx = -INFINITY;
    #pragma unroll
    for (int j = 0; j < 8; ++j) {
        int s = t + j * 256;
        float e = energy[(size_t)b * S_LEN + s];
        if (mask[(size_t)b * S_LEN + s] == 0) e = NEG_INF_F;
        vals[j] = e;
        mx = fmaxf(mx, e);
    }
    #pragma unroll
    for (int m = 1; m < 64; m <<= 1) mx = fmaxf(mx, __shfl_xor(mx, m));
    if (lane == 0) wmax[wid] = mx;
    __syncthreads();
    mx = fmaxf(fmaxf(wmax[0], wmax[1]), fmaxf(wmax[2], wmax[3]));

    float sum = 0.f;
    #pragma unroll
    for (int j = 0; j < 8; ++j) { vals[j] = expf(vals[j] - mx); sum += vals[j]; }
    #pragma unroll
    for (int m = 1; m < 64; m <<= 1) sum += __shfl_xor(sum, m);
    if (lane == 0) wsum[wid] = sum;
    __syncthreads();
    sum = wsum[0] + wsum[1] + wsum[2] + wsum[3];
    float inv = 1.f / sum;
    #pragma unroll
    for (int j = 0; j < 8; ++j)
        attn[(size_t)b * S_LEN + t + j * 256] = vals[j] * inv;
}

// ---------------------------------------------------------------------------
// context[b,e] = sum_s attn[b,s] * x[b,s,e]. Grid (4 e-chunks, 32 b, 16 s-chunks).
// ---------------------------------------------------------------------------
__global__ __launch_bounds__(256) void context_kernel(
    const float* __restrict__ attn, const float* __restrict__ x,
    float* __restrict__ ctx)
{
    int ec = blockIdx.x, b = blockIdx.y, sc = blockIdx.z;
    int e = ec * 256 + threadIdx.x;
    const float* xp = x + ((size_t)b * S_LEN + sc * 128) * KDIM + e;
    const float* ap = attn + (size_t)b * S_LEN + sc * 128;
    float acc = 0.f;
    #pragma unroll 4
    for (int s = 0; s < 128; ++s) acc += ap[s] * xp[(size_t)s * KDIM];
    atomicAdd(&ctx[(size_t)b * KDIM + e], acc);
}

// ---------------------------------------------------------------------------
extern "C" void kernel_launch(void* const* d_in, const int* in_sizes, int n_in,
                              void* d_out, int out_size, void* d_ws, size_t ws_size,
                              hipStream_t stream) {
    const float* dh   = (const float*)d_in[0];  // [32,1024]
    const float* x    = (const float*)d_in[1];  // [32,2048,1024]
    const int*   mask = (const int*)d_in[2];    // [32,2048]
    const float* Wh   = (const float*)d_in[3];  // [1024,1024]
    const float* Ws   = (const float*)d_in[4];  // [1024,1024]
    const float* v    = (const float*)d_in[5];  // [1024]

    float* ctx  = (float*)d_out;                 // [32*1024]
    float* attn = (float*)d_out + 32 * 1024;     // [32*2048]

    unsigned short* Bhi = (unsigned short*)d_ws;   // 1048576 el (2 MB)
    unsigned short* Blo = Bhi + 1048576ull;        // 1048576 el (2 MB)
    float* dec    = (float*)(Blo + 1048576ull);    // 32768 f32
    float* energy = dec + 32768;                   // 65536 f32

    hipMemsetAsync(energy, 0, 65536 * sizeof(float), stream);
    hipMemsetAsync(ctx, 0, 32768 * sizeof(float), stream);

    dec_kernel<<<1024, 256, 0, stream>>>(dh, Ws, dec);
    convert_split<<<512, 256, 0, stream>>>(Wh, Bhi, Blo, 6);   // 64 msubs x 32 ks
    energy_gemm_v3<<<4096, 256, 0, stream>>>(x, Bhi, Blo, dec, v, energy);
    softmax_kernel<<<NBATCH, 256, 0, stream>>>(energy, mask, attn);
    context_kernel<<<dim3(4, NBATCH, 16), 256, 0, stream>>>(attn, x, ctx);
}

// Round 4
// 346.774 us; speedup vs baseline: 2.0102x; 1.2186x over previous
//
#include <hip/hip_runtime.h>
#include <stdint.h>
#include <math.h>

typedef __attribute__((ext_vector_type(8))) short short8;
typedef __attribute__((ext_vector_type(4))) float f32x4;

#define S_LEN 2048
#define NBATCH 32
#define KDIM 1024
#define NEG_INF_F (-1e9f)

#define BM 128
#define BN 128

// round-half-up f32 -> bf16 (equivalent to RNE except exact ties; random data)
__device__ __forceinline__ uint32_t pack_bf16(float f0, float f1) {
    union { float f; uint32_t u; } a, b; a.f = f0; b.f = f1;
    return ((a.u + 0x8000u) >> 16) | ((b.u + 0x8000u) & 0xFFFF0000u);
}

__device__ __forceinline__ void gload_lds16(const unsigned short* g, unsigned short* l) {
    __builtin_amdgcn_global_load_lds(
        (const __attribute__((address_space(1))) void*)g,
        (__attribute__((address_space(3))) void*)l, 16, 0, 0);
}

// ---------------------------------------------------------------------------
// dec[b,e] = sum_d dh[b,d] * Ws[e,d]   (one block per e)
// ---------------------------------------------------------------------------
__global__ __launch_bounds__(256) void dec_kernel(
    const float* __restrict__ dh, const float* __restrict__ Ws,
    float* __restrict__ dec)
{
    __shared__ float wrow[1024];
    int e = blockIdx.x;
    int t = threadIdx.x;
    #pragma unroll
    for (int i = t; i < 1024; i += 256) wrow[i] = Ws[(size_t)e * 1024 + i];
    __syncthreads();
    int b = t >> 3, part = t & 7;
    const float* dhp = dh + (size_t)b * 1024 + part * 128;
    const float* wp  = wrow + part * 128;
    float s = 0.f;
    #pragma unroll 8
    for (int i = 0; i < 128; ++i) s += dhp[i] * wp[i];
    s += __shfl_xor(s, 1);
    s += __shfl_xor(s, 2);
    s += __shfl_xor(s, 4);
    if (part == 0) dec[(size_t)b * 1024 + e] = s;
}

// ---------------------------------------------------------------------------
// One-time B (Wh) convert: f32 -> bf16 (round-nearest), MFMA-fragment-lane
// order per 16x32 subtile. gid = ks*64 + msub, one wave per subtile.
// ---------------------------------------------------------------------------
__global__ __launch_bounds__(256) void convert_hi(
    const float* __restrict__ src, unsigned short* __restrict__ hi)
{
    int gid = blockIdx.x * 4 + (threadIdx.x >> 6);
    int lane = threadIdx.x & 63;
    int ms = gid & 63, ks = gid >> 6;
    const float* p = src + (size_t)(ms * 16 + (lane & 15)) * 1024
                         + ks * 32 + (lane >> 4) * 8;
    f32x4 a = *(const f32x4*)p;
    f32x4 b = *(const f32x4*)(p + 4);
    union { uint32_t d[4]; short8 v; } o;
    o.d[0] = pack_bf16(a.x, a.y); o.d[1] = pack_bf16(a.z, a.w);
    o.d[2] = pack_bf16(b.x, b.y); o.d[3] = pack_bf16(b.z, b.w);
    *(short8*)(hi + (size_t)gid * 512 + lane * 8) = o.v;
}

// ---------------------------------------------------------------------------
// energy GEMM v4: 1-pass bf16 (A-hi x B-hi), double-buffered LDS with
// counted-vmcnt prefetch across barriers (T3 2-phase + T14).
// Tile 128x128, 256 threads (2x2 waves of 64x64). Grid 4096, XCD-swizzled.
// Per k-step/wave: 16 MFMA, 8 ds_read_b128, 2 gload_lds, 2 ds_write_b128.
// ---------------------------------------------------------------------------
__global__ __launch_bounds__(256, 4) void energy_gemm_v4(
    const float* __restrict__ x,            // [65536,1024] f32
    const unsigned short* __restrict__ Bhi, // [32 ks][64 msub][512] bf16
    const float* __restrict__ dec, const float* __restrict__ v,
    float* __restrict__ energy)
{
    // 32 KB: two buffers of [A: 8 subtiles | B: 8 subtiles] x 1 KB
    __shared__ unsigned short lds[16384];

    int bid = blockIdx.x;
    int lid = (bid & 7) * 512 + (bid >> 3);  // 8 N-blocks of an M-block -> same XCD
    int mblk = lid >> 3, nblk = lid & 7;
    int m0 = mblk * BM, n0 = nblk * BN;
    int b = mblk >> 4;                       // 16 mblks per batch row

    int t = threadIdx.x, wid = t >> 6, lane = t & 63;
    int wm = wid >> 1, wn = wid & 1;
    int kg = lane >> 4, lr = lane & 15;

    f32x4 acc[4][4] = {};

    // A staging addresses: thread handles subtile rows (ms0, ms0+4), frag-lane order
    int ms0 = t >> 6, ln = t & 63;
    const float* ap0 = x + (size_t)(m0 + ms0 * 16 + (ln & 15)) * KDIM + (ln >> 4) * 8;
    const float* ap1 = ap0 + (size_t)64 * KDIM;
    int wa0 = ms0 * 512 + ln * 8;
    int wa1 = wa0 + 4 * 512;

    // ---- prologue: A(0) -> regs, issue B(0) -> buf0
    f32x4 a0 = *(const f32x4*)ap0, a1 = *(const f32x4*)(ap0 + 4);
    f32x4 a2 = *(const f32x4*)ap1, a3 = *(const f32x4*)(ap1 + 4);
    #pragma unroll
    for (int i = 0; i < 2; ++i) {
        int c = wid * 2 + i;
        gload_lds16(Bhi + (size_t)(nblk * 8 + c) * 512 + lane * 8, &lds[4096 + c * 512]);
    }

    for (int ks = 0; ks < 32; ++ks) {
        int cur = ks & 1;
        unsigned short* bufA = &lds[cur * 8192];
        unsigned short* bufB = bufA + 4096;

        // pack & ds_write A(ks) into current buffer (compiler waits the reg loads)
        {
            union { uint32_t d[4]; short8 v; } o;
            o.d[0] = pack_bf16(a0.x, a0.y); o.d[1] = pack_bf16(a0.z, a0.w);
            o.d[2] = pack_bf16(a1.x, a1.y); o.d[3] = pack_bf16(a1.z, a1.w);
            *(short8*)&bufA[wa0] = o.v;
            o.d[0] = pack_bf16(a2.x, a2.y); o.d[1] = pack_bf16(a2.z, a2.w);
            o.d[2] = pack_bf16(a3.x, a3.y); o.d[3] = pack_bf16(a3.z, a3.w);
            *(short8*)&bufA[wa1] = o.v;
        }

        if (ks < 31) {
            // prefetch A(ks+1) -> regs, B(ks+1) -> other buffer  [+6 vm ops]
            const float* p0 = ap0 + (ks + 1) * 32;
            const float* p1 = ap1 + (ks + 1) * 32;
            a0 = *(const f32x4*)p0; a1 = *(const f32x4*)(p0 + 4);
            a2 = *(const f32x4*)p1; a3 = *(const f32x4*)(p1 + 4);
            unsigned short* nbufB = &lds[(cur ^ 1) * 8192 + 4096];
            #pragma unroll
            for (int i = 0; i < 2; ++i) {
                int c = wid * 2 + i;
                gload_lds16(Bhi + (size_t)((ks + 1) * 64 + nblk * 8 + c) * 512 + lane * 8,
                            &nbufB[c * 512]);
            }
            // retire B(ks) (6 newer prefetch ops stay in flight); A-writes done
            asm volatile("s_waitcnt vmcnt(6) lgkmcnt(0)" ::: "memory");
        } else {
            asm volatile("s_waitcnt vmcnt(0) lgkmcnt(0)" ::: "memory");
        }
        __builtin_amdgcn_s_barrier();   // B1: buf[cur] fully staged, all waves

        short8 bf[4];
        #pragma unroll
        for (int ni = 0; ni < 4; ++ni)
            bf[ni] = *(const short8*)&bufB[(wn * 4 + ni) * 512 + lane * 8];
        #pragma unroll
        for (int mi = 0; mi < 4; ++mi) {
            short8 af = *(const short8*)&bufA[(wm * 4 + mi) * 512 + lane * 8];
            #pragma unroll
            for (int ni = 0; ni < 4; ++ni)
                acc[mi][ni] = __builtin_amdgcn_mfma_f32_16x16x32_bf16(af, bf[ni], acc[mi][ni], 0, 0, 0);
        }
        __builtin_amdgcn_s_barrier();   // B2: reads of buf[cur] done before it's rewritten
    }

    // ---- epilogue: energy[m] += sum_n tanh(enc + dec) * v
    float vv[4], dd[4];
    #pragma unroll
    for (int ni = 0; ni < 4; ++ni) {
        int d = n0 + wn * 64 + ni * 16 + lr;
        vv[ni] = v[d];
        dd[ni] = dec[(size_t)b * 1024 + d];
    }
    #pragma unroll
    for (int mi = 0; mi < 4; ++mi) {
        #pragma unroll
        for (int r = 0; r < 4; ++r) {
            float local = 0.f;
            #pragma unroll
            for (int ni = 0; ni < 4; ++ni)
                local += tanhf(acc[mi][ni][r] + dd[ni]) * vv[ni];
            local += __shfl_xor(local, 1);
            local += __shfl_xor(local, 2);
            local += __shfl_xor(local, 4);
            local += __shfl_xor(local, 8);
            if (lr == 0) {
                int m = m0 + wm * 64 + mi * 16 + kg * 4 + r;
                atomicAdd(&energy[m], local);
            }
        }
    }
}

// ---------------------------------------------------------------------------
// Masked softmax over S per batch row. One block per b.
// ---------------------------------------------------------------------------
__global__ __launch_bounds__(256) void softmax_kernel(
    const float* __restrict__ energy, const int* __restrict__ mask,
    float* __restrict__ attn)
{
    int b = blockIdx.x;
    int t = threadIdx.x;
    int wid = t >> 6, lane = t & 63;
    __shared__ float wmax[4], wsum[4];

    float vals[8];
    float mx = -INFINITY;
    #pragma unroll
    for (int j = 0; j < 8; ++j) {
        int s = t + j * 256;
        float e = energy[(size_t)b * S_LEN + s];
        if (mask[(size_t)b * S_LEN + s] == 0) e = NEG_INF_F;
        vals[j] = e;
        mx = fmaxf(mx, e);
    }
    #pragma unroll
    for (int m = 1; m < 64; m <<= 1) mx = fmaxf(mx, __shfl_xor(mx, m));
    if (lane == 0) wmax[wid] = mx;
    __syncthreads();
    mx = fmaxf(fmaxf(wmax[0], wmax[1]), fmaxf(wmax[2], wmax[3]));

    float sum = 0.f;
    #pragma unroll
    for (int j = 0; j < 8; ++j) { vals[j] = expf(vals[j] - mx); sum += vals[j]; }
    #pragma unroll
    for (int m = 1; m < 64; m <<= 1) sum += __shfl_xor(sum, m);
    if (lane == 0) wsum[wid] = sum;
    __syncthreads();
    sum = wsum[0] + wsum[1] + wsum[2] + wsum[3];
    float inv = 1.f / sum;
    #pragma unroll
    for (int j = 0; j < 8; ++j)
        attn[(size_t)b * S_LEN + t + j * 256] = vals[j] * inv;
}

// ---------------------------------------------------------------------------
// context[b,e] = sum_s attn[b,s] * x[b,s,e]. Grid (4 e-chunks, 32 b, 16 s-chunks).
// ---------------------------------------------------------------------------
__global__ __launch_bounds__(256) void context_kernel(
    const float* __restrict__ attn, const float* __restrict__ x,
    float* __restrict__ ctx)
{
    int ec = blockIdx.x, b = blockIdx.y, sc = blockIdx.z;
    int e = ec * 256 + threadIdx.x;
    const float* xp = x + ((size_t)b * S_LEN + sc * 128) * KDIM + e;
    const float* ap = attn + (size_t)b * S_LEN + sc * 128;
    float acc = 0.f;
    #pragma unroll 4
    for (int s = 0; s < 128; ++s) acc += ap[s] * xp[(size_t)s * KDIM];
    atomicAdd(&ctx[(size_t)b * KDIM + e], acc);
}

// ---------------------------------------------------------------------------
extern "C" void kernel_launch(void* const* d_in, const int* in_sizes, int n_in,
                              void* d_out, int out_size, void* d_ws, size_t ws_size,
                              hipStream_t stream) {
    const float* dh   = (const float*)d_in[0];  // [32,1024]
    const float* x    = (const float*)d_in[1];  // [32,2048,1024]
    const int*   mask = (const int*)d_in[2];    // [32,2048]
    const float* Wh   = (const float*)d_in[3];  // [1024,1024]
    const float* Ws   = (const float*)d_in[4];  // [1024,1024]
    const float* v    = (const float*)d_in[5];  // [1024]

    float* ctx  = (float*)d_out;                 // [32*1024]
    float* attn = (float*)d_out + 32 * 1024;     // [32*2048]

    unsigned short* Bhi = (unsigned short*)d_ws;   // 1048576 el (2 MB)
    float* dec    = (float*)(Bhi + 1048576ull);    // 32768 f32
    float* energy = dec + 32768;                   // 65536 f32

    hipMemsetAsync(energy, 0, 65536 * sizeof(float), stream);
    hipMemsetAsync(ctx, 0, 32768 * sizeof(float), stream);

    dec_kernel<<<1024, 256, 0, stream>>>(dh, Ws, dec);
    convert_hi<<<512, 256, 0, stream>>>(Wh, Bhi);   // 64 msubs x 32 ks
    energy_gemm_v4<<<4096, 256, 0, stream>>>(x, Bhi, dec, v, energy);
    softmax_kernel<<<NBATCH, 256, 0, stream>>>(energy, mask, attn);
    context_kernel<<<dim3(4, NBATCH, 16), 256, 0, stream>>>(attn, x, ctx);
}

// Round 5
// 318.825 us; speedup vs baseline: 2.1864x; 1.0877x over previous
//
#include <hip/hip_runtime.h>
#include <stdint.h>
#include <math.h>

typedef __attribute__((ext_vector_type(8))) short short8;
typedef __attribute__((ext_vector_type(4))) float f32x4;

#define S_LEN 2048
#define NBATCH 32
#define KDIM 1024
#define NEG_INF_F (-1e9f)

#define BM 128
#define BN 128

// round-half-up f32 -> bf16, two at a time, packed into one dword
__device__ __forceinline__ uint32_t pack_bf16(float f0, float f1) {
    union { float f; uint32_t u; } a, b; a.f = f0; b.f = f1;
    return ((a.u + 0x8000u) >> 16) | ((b.u + 0x8000u) & 0xFFFF0000u);
}

__device__ __forceinline__ void gload_lds16(const unsigned short* g, unsigned short* l) {
    __builtin_amdgcn_global_load_lds(
        (const __attribute__((address_space(1))) void*)g,
        (__attribute__((address_space(3))) void*)l, 16, 0, 0);
}

// ---------------------------------------------------------------------------
// dec[b,e] = sum_d dh[b,d] * Ws[e,d]   (one block per e)
// ---------------------------------------------------------------------------
__global__ __launch_bounds__(256) void dec_kernel(
    const float* __restrict__ dh, const float* __restrict__ Ws,
    float* __restrict__ dec)
{
    __shared__ float wrow[1024];
    int e = blockIdx.x;
    int t = threadIdx.x;
    #pragma unroll
    for (int i = t; i < 1024; i += 256) wrow[i] = Ws[(size_t)e * 1024 + i];
    __syncthreads();
    int b = t >> 3, part = t & 7;
    const float* dhp = dh + (size_t)b * 1024 + part * 128;
    const float* wp  = wrow + part * 128;
    float s = 0.f;
    #pragma unroll 8
    for (int i = 0; i < 128; ++i) s += dhp[i] * wp[i];
    s += __shfl_xor(s, 1);
    s += __shfl_xor(s, 2);
    s += __shfl_xor(s, 4);
    if (part == 0) dec[(size_t)b * 1024 + e] = s;
}

// ---------------------------------------------------------------------------
// One-shot f32 -> bf16 convert into MFMA-fragment-lane order per 16x32
// subtile:  out[gid*512 + lane*8 + j], gid = ks*nmsub + ms,
//   src[(ms*16 + (lane&15))*1024 + ks*32 + (lane>>4)*8 + j]
// One wave per subtile, 4 waves per block.
// ---------------------------------------------------------------------------
__global__ __launch_bounds__(256) void convert_frag(
    const float* __restrict__ src, unsigned short* __restrict__ hi, int lg_nmsub)
{
    int gid = blockIdx.x * 4 + (threadIdx.x >> 6);
    int lane = threadIdx.x & 63;
    int ms = gid & ((1 << lg_nmsub) - 1);
    int ks = gid >> lg_nmsub;
    const float* p = src + (size_t)(ms * 16 + (lane & 15)) * 1024
                         + ks * 32 + (lane >> 4) * 8;
    f32x4 a = *(const f32x4*)p;
    f32x4 b = *(const f32x4*)(p + 4);
    union { uint32_t d[4]; short8 v; } o;
    o.d[0] = pack_bf16(a.x, a.y); o.d[1] = pack_bf16(a.z, a.w);
    o.d[2] = pack_bf16(b.x, b.y); o.d[3] = pack_bf16(b.z, b.w);
    *(short8*)(hi + (size_t)gid * 512 + lane * 8) = o.v;
}

// ---------------------------------------------------------------------------
// energy GEMM v5: both operands pre-converted bf16 in fragment order.
// Pure global_load_lds staging (16 x 1KB chunks / k-step, 4 per wave),
// double-buffered LDS, counted-vmcnt 2-phase prefetch. Zero in-loop VALU
// conversion. Tile 128x128, 256 threads (2x2 waves of 64x64). Grid 4096.
// ---------------------------------------------------------------------------
__global__ __launch_bounds__(256, 4) void energy_gemm_v5(
    const unsigned short* __restrict__ Ahi,  // [32 ks][4096 msub][512]
    const unsigned short* __restrict__ Bhi,  // [32 ks][64 nsub][512]
    const float* __restrict__ dec, const float* __restrict__ v,
    float* __restrict__ energy)
{
    // 32 KB: two buffers of [A: 8 subtiles | B: 8 subtiles] x 1 KB
    __shared__ unsigned short lds[16384];

    int bid = blockIdx.x;
    int lid = (bid & 7) * 512 + (bid >> 3);  // 8 N-blocks of an M-block -> same XCD
    int mblk = lid >> 3, nblk = lid & 7;
    int m0 = mblk * BM, n0 = nblk * BN;
    int b = mblk >> 4;                       // 16 mblks per batch row

    int t = threadIdx.x, wid = t >> 6, lane = t & 63;
    int wm = wid >> 1, wn = wid & 1;
    int kg = lane >> 4, lr = lane & 15;

    f32x4 acc[4][4] = {};

    // ---- prologue: stage tile 0 into buf0
    {
        unsigned short* buf = &lds[0];
        #pragma unroll
        for (int i = 0; i < 4; ++i) {
            int c = wid * 4 + i;
            const unsigned short* g = (c < 8)
                ? Ahi + ((size_t)0 * 4096 + mblk * 8 + c) * 512
                : Bhi + ((size_t)0 * 64 + nblk * 8 + (c - 8)) * 512;
            gload_lds16(g + lane * 8, &buf[c * 512]);
        }
    }

    for (int ks = 0; ks < 32; ++ks) {
        unsigned short* bufA = &lds[(ks & 1) * 8192];
        unsigned short* bufB = bufA + 4096;

        if (ks < 31) {
            // prefetch tile ks+1 into the other buffer (4 vm ops per wave)
            unsigned short* nbuf = &lds[((ks + 1) & 1) * 8192];
            #pragma unroll
            for (int i = 0; i < 4; ++i) {
                int c = wid * 4 + i;
                const unsigned short* g = (c < 8)
                    ? Ahi + ((size_t)(ks + 1) * 4096 + mblk * 8 + c) * 512
                    : Bhi + ((size_t)(ks + 1) * 64 + nblk * 8 + (c - 8)) * 512;
                gload_lds16(g + lane * 8, &nbuf[c * 512]);
            }
            // retire tile ks's 4 loads; ks+1's 4 stay in flight across barrier
            asm volatile("s_waitcnt vmcnt(4)" ::: "memory");
        } else {
            asm volatile("s_waitcnt vmcnt(0)" ::: "memory");
        }
        __builtin_amdgcn_s_barrier();   // buf[ks&1] fully staged for all waves

        short8 bf[4];
        #pragma unroll
        for (int ni = 0; ni < 4; ++ni)
            bf[ni] = *(const short8*)&bufB[(wn * 4 + ni) * 512 + lane * 8];
        #pragma unroll
        for (int mi = 0; mi < 4; ++mi) {
            short8 af = *(const short8*)&bufA[(wm * 4 + mi) * 512 + lane * 8];
            #pragma unroll
            for (int ni = 0; ni < 4; ++ni)
                acc[mi][ni] = __builtin_amdgcn_mfma_f32_16x16x32_bf16(af, bf[ni], acc[mi][ni], 0, 0, 0);
        }
        __builtin_amdgcn_s_barrier();   // reads of buf[ks&1] done before rewrite
    }

    // ---- epilogue: energy[m] += sum_n tanh(enc + dec) * v
    float vv[4], dd[4];
    #pragma unroll
    for (int ni = 0; ni < 4; ++ni) {
        int d = n0 + wn * 64 + ni * 16 + lr;
        vv[ni] = v[d];
        dd[ni] = dec[(size_t)b * 1024 + d];
    }
    #pragma unroll
    for (int mi = 0; mi < 4; ++mi) {
        #pragma unroll
        for (int r = 0; r < 4; ++r) {
            float local = 0.f;
            #pragma unroll
            for (int ni = 0; ni < 4; ++ni)
                local += tanhf(acc[mi][ni][r] + dd[ni]) * vv[ni];
            local += __shfl_xor(local, 1);
            local += __shfl_xor(local, 2);
            local += __shfl_xor(local, 4);
            local += __shfl_xor(local, 8);
            if (lr == 0) {
                int m = m0 + wm * 64 + mi * 16 + kg * 4 + r;
                atomicAdd(&energy[m], local);
            }
        }
    }
}

// ---------------------------------------------------------------------------
// Masked softmax over S per batch row. One block per b.
// ---------------------------------------------------------------------------
__global__ __launch_bounds__(256) void softmax_kernel(
    const float* __restrict__ energy, const int* __restrict__ mask,
    float* __restrict__ attn)
{
    int b = blockIdx.x;
    int t = threadIdx.x;
    int wid = t >> 6, lane = t & 63;
    __shared__ float wmax[4], wsum[4];

    float vals[8];
    float mx = -INFINITY;
    #pragma unroll
    for (int j = 0; j < 8; ++j) {
        int s = t + j * 256;
        float e = energy[(size_t)b * S_LEN + s];
        if (mask[(size_t)b * S_LEN + s] == 0) e = NEG_INF_F;
        vals[j] = e;
        mx = fmaxf(mx, e);
    }
    #pragma unroll
    for (int m = 1; m < 64; m <<= 1) mx = fmaxf(mx, __shfl_xor(mx, m));
    if (lane == 0) wmax[wid] = mx;
    __syncthreads();
    mx = fmaxf(fmaxf(wmax[0], wmax[1]), fmaxf(wmax[2], wmax[3]));

    float sum = 0.f;
    #pragma unroll
    for (int j = 0; j < 8; ++j) { vals[j] = expf(vals[j] - mx); sum += vals[j]; }
    #pragma unroll
    for (int m = 1; m < 64; m <<= 1) sum += __shfl_xor(sum, m);
    if (lane == 0) wsum[wid] = sum;
    __syncthreads();
    sum = wsum[0] + wsum[1] + wsum[2] + wsum[3];
    float inv = 1.f / sum;
    #pragma unroll
    for (int j = 0; j < 8; ++j)
        attn[(size_t)b * S_LEN + t + j * 256] = vals[j] * inv;
}

// ---------------------------------------------------------------------------
// context[b,e] = sum_s attn[b,s] * x[b,s,e]. Grid (4 e-chunks, 32 b, 16 s-chunks).
// ---------------------------------------------------------------------------
__global__ __launch_bounds__(256) void context_kernel(
    const float* __restrict__ attn, const float* __restrict__ x,
    float* __restrict__ ctx)
{
    int ec = blockIdx.x, b = blockIdx.y, sc = blockIdx.z;
    int e = ec * 256 + threadIdx.x;
    const float* xp = x + ((size_t)b * S_LEN + sc * 128) * KDIM + e;
    const float* ap = attn + (size_t)b * S_LEN + sc * 128;
    float acc = 0.f;
    #pragma unroll 4
    for (int s = 0; s < 128; ++s) acc += ap[s] * xp[(size_t)s * KDIM];
    atomicAdd(&ctx[(size_t)b * KDIM + e], acc);
}

// ---------------------------------------------------------------------------
extern "C" void kernel_launch(void* const* d_in, const int* in_sizes, int n_in,
                              void* d_out, int out_size, void* d_ws, size_t ws_size,
                              hipStream_t stream) {
    const float* dh   = (const float*)d_in[0];  // [32,1024]
    const float* x    = (const float*)d_in[1];  // [32,2048,1024]
    const int*   mask = (const int*)d_in[2];    // [32,2048]
    const float* Wh   = (const float*)d_in[3];  // [1024,1024]
    const float* Ws   = (const float*)d_in[4];  // [1024,1024]
    const float* v    = (const float*)d_in[5];  // [1024]

    float* ctx  = (float*)d_out;                 // [32*1024]
    float* attn = (float*)d_out + 32 * 1024;     // [32*2048]

    unsigned short* Ahi = (unsigned short*)d_ws;   // 67108864 el (128 MB)
    unsigned short* Bhi = Ahi + 67108864ull;       // 1048576 el (2 MB)
    float* dec    = (float*)(Bhi + 1048576ull);    // 32768 f32
    float* energy = dec + 32768;                   // 65536 f32

    hipMemsetAsync(energy, 0, 65536 * sizeof(float), stream);
    hipMemsetAsync(ctx, 0, 32768 * sizeof(float), stream);

    dec_kernel<<<1024, 256, 0, stream>>>(dh, Ws, dec);
    convert_frag<<<512, 256, 0, stream>>>(Wh, Bhi, 6);     // 64 nsubs x 32 ks
    convert_frag<<<32768, 256, 0, stream>>>(x, Ahi, 12);   // 4096 msubs x 32 ks
    energy_gemm_v5<<<4096, 256, 0, stream>>>(Ahi, Bhi, dec, v, energy);
    softmax_kernel<<<NBATCH, 256, 0, stream>>>(energy, mask, attn);
    context_kernel<<<dim3(4, NBATCH, 16), 256, 0, stream>>>(attn, x, ctx);
}

// Round 6
// 317.285 us; speedup vs baseline: 2.1970x; 1.0049x over previous
//
#include <hip/hip_runtime.h>
#include <stdint.h>
#include <math.h>

typedef __attribute__((ext_vector_type(8))) short short8;
typedef __attribute__((ext_vector_type(4))) float f32x4;

#define S_LEN 2048
#define NBATCH 32
#define KDIM 1024
#define NEG_INF_F (-1e9f)

#define BM 256
#define BN 256

// round-half-up f32 -> bf16, two at a time, packed into one dword
__device__ __forceinline__ uint32_t pack_bf16(float f0, float f1) {
    union { float f; uint32_t u; } a, b; a.f = f0; b.f = f1;
    return ((a.u + 0x8000u) >> 16) | ((b.u + 0x8000u) & 0xFFFF0000u);
}

__device__ __forceinline__ void gload_lds16(const unsigned short* g, unsigned short* l) {
    __builtin_amdgcn_global_load_lds(
        (const __attribute__((address_space(1))) void*)g,
        (__attribute__((address_space(3))) void*)l, 16, 0, 0);
}

// tanh(x) = 1 - 2/(exp(2x)+1); __expf -> v_exp_f32, rcp -> v_rcp_f32 (~1e-7)
__device__ __forceinline__ float fast_tanh(float x) {
    float e = __expf(2.0f * x);
    return 1.0f - 2.0f * __builtin_amdgcn_rcpf(e + 1.0f);
}

// ---------------------------------------------------------------------------
// dec[b,e] = sum_d dh[b,d] * Ws[e,d]   (one block per e)
// ---------------------------------------------------------------------------
__global__ __launch_bounds__(256) void dec_kernel(
    const float* __restrict__ dh, const float* __restrict__ Ws,
    float* __restrict__ dec)
{
    __shared__ float wrow[1024];
    int e = blockIdx.x;
    int t = threadIdx.x;
    #pragma unroll
    for (int i = t; i < 1024; i += 256) wrow[i] = Ws[(size_t)e * 1024 + i];
    __syncthreads();
    int b = t >> 3, part = t & 7;
    const float* dhp = dh + (size_t)b * 1024 + part * 128;
    const float* wp  = wrow + part * 128;
    float s = 0.f;
    #pragma unroll 8
    for (int i = 0; i < 128; ++i) s += dhp[i] * wp[i];
    s += __shfl_xor(s, 1);
    s += __shfl_xor(s, 2);
    s += __shfl_xor(s, 4);
    if (part == 0) dec[(size_t)b * 1024 + e] = s;
}

// ---------------------------------------------------------------------------
// One-shot f32 -> bf16 convert into MFMA-fragment-lane order per 16x32
// subtile:  out[gid*512 + lane*8 + j], gid = ks*nmsub + ms,
//   src[(ms*16 + (lane&15))*1024 + ks*32 + (lane>>4)*8 + j]
// ---------------------------------------------------------------------------
__global__ __launch_bounds__(256) void convert_frag(
    const float* __restrict__ src, unsigned short* __restrict__ hi, int lg_nmsub)
{
    int gid = blockIdx.x * 4 + (threadIdx.x >> 6);
    int lane = threadIdx.x & 63;
    int ms = gid & ((1 << lg_nmsub) - 1);
    int ks = gid >> lg_nmsub;
    const float* p = src + (size_t)(ms * 16 + (lane & 15)) * 1024
                         + ks * 32 + (lane >> 4) * 8;
    f32x4 a = *(const f32x4*)p;
    f32x4 b = *(const f32x4*)(p + 4);
    union { uint32_t d[4]; short8 v; } o;
    o.d[0] = pack_bf16(a.x, a.y); o.d[1] = pack_bf16(a.z, a.w);
    o.d[2] = pack_bf16(b.x, b.y); o.d[3] = pack_bf16(b.z, b.w);
    *(short8*)(hi + (size_t)gid * 512 + lane * 8) = o.v;
}

// ---------------------------------------------------------------------------
// energy GEMM v6: 256x256 tile, 8 waves (2x4, wave tile 128x64), BK=32.
// Fragment-ordered bf16 operands, pure global_load_lds staging (4/wave/step),
// double-buffered linear LDS (64 KB), SINGLE barrier per K-step:
//   issue next-tile stages -> MFMA on cur -> vmcnt(0) -> barrier.
// Hazards: buf[nxt]'s prior readers finished before the barrier that preceded
// this iteration's stage-issue; each wave's ds_reads are consumed by MFMA
// (lgkmcnt) before it reaches the barrier.
// Grid 1024 = 256 M-blocks x 4 N-blocks, XCD-swizzled.
// ---------------------------------------------------------------------------
__global__ __launch_bounds__(512, 2) void energy_gemm_v6(
    const unsigned short* __restrict__ Ahi,  // [32 ks][4096 msub][512]
    const unsigned short* __restrict__ Bhi,  // [32 ks][64 nsub][512]
    const float* __restrict__ dec, const float* __restrict__ v,
    float* __restrict__ energy)
{
    // 64 KB: two buffers of [A: 16 subtiles | B: 16 subtiles] x 1 KB
    __shared__ unsigned short lds[32768];

    int bid = blockIdx.x;
    int lid = (bid & 7) * 128 + (bid >> 3);  // 4 N-blocks of an M-block -> same XCD
    int mblk = lid >> 2, nblk = lid & 3;
    int m0 = mblk * BM, n0 = nblk * BN;
    int b = m0 >> 11;                        // 2048 rows per batch

    int t = threadIdx.x, wid = t >> 6, lane = t & 63;
    int wm = wid >> 2, wn = wid & 3;         // 2 x 4 waves, wave tile 128 x 64
    int kg = lane >> 4, lr = lane & 15;

    f32x4 acc[8][4] = {};

    // ---- prologue: stage tile 0 into buf0
    #pragma unroll
    for (int i = 0; i < 4; ++i) {
        int c = wid * 4 + i;
        const unsigned short* g = (c < 16)
            ? Ahi + ((size_t)mblk * 16 + c) * 512
            : Bhi + ((size_t)nblk * 16 + (c - 16)) * 512;
        gload_lds16(g + lane * 8, &lds[c * 512]);
    }
    asm volatile("s_waitcnt vmcnt(0)" ::: "memory");
    __builtin_amdgcn_s_barrier();

    for (int ks = 0; ks < 32; ++ks) {
        unsigned short* bufA = &lds[(ks & 1) * 16384];
        unsigned short* bufB = bufA + 8192;

        if (ks < 31) {
            // issue next tile's stages into the other buffer (4 per wave)
            unsigned short* nbuf = &lds[((ks + 1) & 1) * 16384];
            #pragma unroll
            for (int i = 0; i < 4; ++i) {
                int c = wid * 4 + i;
                const unsigned short* g = (c < 16)
                    ? Ahi + ((size_t)(ks + 1) * 4096 + mblk * 16 + c) * 512
                    : Bhi + ((size_t)(ks + 1) * 64 + nblk * 16 + (c - 16)) * 512;
                gload_lds16(g + lane * 8, &nbuf[c * 512]);
            }
        }

        // ---- compute on buf[cur]: 12 ds_read_b128, 32 MFMA per wave
        short8 bf[4];
        #pragma unroll
        for (int ni = 0; ni < 4; ++ni)
            bf[ni] = *(const short8*)&bufB[(wn * 4 + ni) * 512 + lane * 8];
        #pragma unroll
        for (int mi = 0; mi < 8; ++mi) {
            short8 af = *(const short8*)&bufA[(wm * 8 + mi) * 512 + lane * 8];
            #pragma unroll
            for (int ni = 0; ni < 4; ++ni)
                acc[mi][ni] = __builtin_amdgcn_mfma_f32_16x16x32_bf16(af, bf[ni], acc[mi][ni], 0, 0, 0);
        }

        // next-tile loads (issued ~32 MFMA ago) retire; then block-wide sync
        asm volatile("s_waitcnt vmcnt(0)" ::: "memory");
        __builtin_amdgcn_s_barrier();
    }

    // ---- epilogue: energy[m] += sum_n tanh(enc + dec) * v
    float vv[4], dd[4];
    #pragma unroll
    for (int ni = 0; ni < 4; ++ni) {
        int d = n0 + wn * 64 + ni * 16 + lr;
        vv[ni] = v[d];
        dd[ni] = dec[(size_t)b * 1024 + d];
    }
    #pragma unroll
    for (int mi = 0; mi < 8; ++mi) {
        #pragma unroll
        for (int r = 0; r < 4; ++r) {
            float local = 0.f;
            #pragma unroll
            for (int ni = 0; ni < 4; ++ni)
                local += fast_tanh(acc[mi][ni][r] + dd[ni]) * vv[ni];
            local += __shfl_xor(local, 1);
            local += __shfl_xor(local, 2);
            local += __shfl_xor(local, 4);
            local += __shfl_xor(local, 8);
            if (lr == 0) {
                int m = m0 + wm * 128 + mi * 16 + kg * 4 + r;
                atomicAdd(&energy[m], local);
            }
        }
    }
}

// ---------------------------------------------------------------------------
// Masked softmax over S per batch row. One block per b.
// ---------------------------------------------------------------------------
__global__ __launch_bounds__(256) void softmax_kernel(
    const float* __restrict__ energy, const int* __restrict__ mask,
    float* __restrict__ attn)
{
    int b = blockIdx.x;
    int t = threadIdx.x;
    int wid = t >> 6, lane = t & 63;
    __shared__ float wmax[4], wsum[4];

    float vals[8];
    float mx = -INFINITY;
    #pragma unroll
    for (int j = 0; j < 8; ++j) {
        int s = t + j * 256;
        float e = energy[(size_t)b * S_LEN + s];
        if (mask[(size_t)b * S_LEN + s] == 0) e = NEG_INF_F;
        vals[j] = e;
        mx = fmaxf(mx, e);
    }
    #pragma unroll
    for (int m = 1; m < 64; m <<= 1) mx = fmaxf(mx, __shfl_xor(mx, m));
    if (lane == 0) wmax[wid] = mx;
    __syncthreads();
    mx = fmaxf(fmaxf(wmax[0], wmax[1]), fmaxf(wmax[2], wmax[3]));

    float sum = 0.f;
    #pragma unroll
    for (int j = 0; j < 8; ++j) { vals[j] = expf(vals[j] - mx); sum += vals[j]; }
    #pragma unroll
    for (int m = 1; m < 64; m <<= 1) sum += __shfl_xor(sum, m);
    if (lane == 0) wsum[wid] = sum;
    __syncthreads();
    sum = wsum[0] + wsum[1] + wsum[2] + wsum[3];
    float inv = 1.f / sum;
    #pragma unroll
    for (int j = 0; j < 8; ++j)
        attn[(size_t)b * S_LEN + t + j * 256] = vals[j] * inv;
}

// ---------------------------------------------------------------------------
// context[b,e] = sum_s attn[b,s] * x[b,s,e]. Grid (4 e-chunks, 32 b, 16 s-chunks).
// ---------------------------------------------------------------------------
__global__ __launch_bounds__(256) void context_kernel(
    const float* __restrict__ attn, const float* __restrict__ x,
    float* __restrict__ ctx)
{
    int ec = blockIdx.x, b = blockIdx.y, sc = blockIdx.z;
    int e = ec * 256 + threadIdx.x;
    const float* xp = x + ((size_t)b * S_LEN + sc * 128) * KDIM + e;
    const float* ap = attn + (size_t)b * S_LEN + sc * 128;
    float acc = 0.f;
    #pragma unroll 4
    for (int s = 0; s < 128; ++s) acc += ap[s] * xp[(size_t)s * KDIM];
    atomicAdd(&ctx[(size_t)b * KDIM + e], acc);
}

// ---------------------------------------------------------------------------
extern "C" void kernel_launch(void* const* d_in, const int* in_sizes, int n_in,
                              void* d_out, int out_size, void* d_ws, size_t ws_size,
                              hipStream_t stream) {
    const float* dh   = (const float*)d_in[0];  // [32,1024]
    const float* x    = (const float*)d_in[1];  // [32,2048,1024]
    const int*   mask = (const int*)d_in[2];    // [32,2048]
    const float* Wh   = (const float*)d_in[3];  // [1024,1024]
    const float* Ws   = (const float*)d_in[4];  // [1024,1024]
    const float* v    = (const float*)d_in[5];  // [1024]

    float* ctx  = (float*)d_out;                 // [32*1024]
    float* attn = (float*)d_out + 32 * 1024;     // [32*2048]

    unsigned short* Ahi = (unsigned short*)d_ws;   // 67108864 el (128 MB)
    unsigned short* Bhi = Ahi + 67108864ull;       // 1048576 el (2 MB)
    float* dec    = (float*)(Bhi + 1048576ull);    // 32768 f32
    float* energy = dec + 32768;                   // 65536 f32

    hipMemsetAsync(energy, 0, 65536 * sizeof(float), stream);
    hipMemsetAsync(ctx, 0, 32768 * sizeof(float), stream);

    dec_kernel<<<1024, 256, 0, stream>>>(dh, Ws, dec);
    convert_frag<<<512, 256, 0, stream>>>(Wh, Bhi, 6);     // 64 nsubs x 32 ks
    convert_frag<<<32768, 256, 0, stream>>>(x, Ahi, 12);   // 4096 msubs x 32 ks
    energy_gemm_v6<<<1024, 512, 0, stream>>>(Ahi, Bhi, dec, v, energy);
    softmax_kernel<<<NBATCH, 256, 0, stream>>>(energy, mask, attn);
    context_kernel<<<dim3(4, NBATCH, 16), 256, 0, stream>>>(attn, x, ctx);
}

// Round 7
// 311.376 us; speedup vs baseline: 2.2387x; 1.0190x over previous
//
#include <hip/hip_runtime.h>
#include <stdint.h>
#include <math.h>

typedef __attribute__((ext_vector_type(8))) short short8;
typedef __attribute__((ext_vector_type(4))) float f32x4;

#define S_LEN 2048
#define NBATCH 32
#define KDIM 1024
#define NEG_INF_F (-1e9f)

#define BM 256
#define BN 256

// round-half-up f32 -> bf16, two at a time, packed into one dword
__device__ __forceinline__ uint32_t pack_bf16(float f0, float f1) {
    union { float f; uint32_t u; } a, b; a.f = f0; b.f = f1;
    return ((a.u + 0x8000u) >> 16) | ((b.u + 0x8000u) & 0xFFFF0000u);
}

__device__ __forceinline__ void gload_lds16(const unsigned short* g, unsigned short* l) {
    __builtin_amdgcn_global_load_lds(
        (const __attribute__((address_space(1))) void*)g,
        (__attribute__((address_space(3))) void*)l, 16, 0, 0);
}

// tanh(x) = 1 - 2/(exp(2x)+1); __expf -> v_exp_f32, rcp -> v_rcp_f32 (~1e-7)
__device__ __forceinline__ float fast_tanh(float x) {
    float e = __expf(2.0f * x);
    return 1.0f - 2.0f * __builtin_amdgcn_rcpf(e + 1.0f);
}

// ---------------------------------------------------------------------------
// dec[b,e] = sum_d dh[b,d] * Ws[e,d]   (one block per e)
// ---------------------------------------------------------------------------
__global__ __launch_bounds__(256) void dec_kernel(
    const float* __restrict__ dh, const float* __restrict__ Ws,
    float* __restrict__ dec)
{
    __shared__ float wrow[1024];
    int e = blockIdx.x;
    int t = threadIdx.x;
    #pragma unroll
    for (int i = t; i < 1024; i += 256) wrow[i] = Ws[(size_t)e * 1024 + i];
    __syncthreads();
    int b = t >> 3, part = t & 7;
    const float* dhp = dh + (size_t)b * 1024 + part * 128;
    const float* wp  = wrow + part * 128;
    float s = 0.f;
    #pragma unroll 8
    for (int i = 0; i < 128; ++i) s += dhp[i] * wp[i];
    s += __shfl_xor(s, 1);
    s += __shfl_xor(s, 2);
    s += __shfl_xor(s, 4);
    if (part == 0) dec[(size_t)b * 1024 + e] = s;
}

// ---------------------------------------------------------------------------
// B (Wh) one-shot f32->bf16 into fragment-lane order. gid = ks*64 + nsub.
// ---------------------------------------------------------------------------
__global__ __launch_bounds__(256) void convert_frag_B(
    const float* __restrict__ src, unsigned short* __restrict__ out)
{
    int gid = blockIdx.x * 4 + (threadIdx.x >> 6);
    int lane = threadIdx.x & 63;
    int ms = gid & 63, ks = gid >> 6;
    const float* p = src + (size_t)(ms * 16 + (lane & 15)) * 1024
                         + ks * 32 + (lane >> 4) * 8;
    f32x4 a = *(const f32x4*)p;
    f32x4 b = *(const f32x4*)(p + 4);
    union { uint32_t d[4]; short8 v; } o;
    o.d[0] = pack_bf16(a.x, a.y); o.d[1] = pack_bf16(a.z, a.w);
    o.d[2] = pack_bf16(b.x, b.y); o.d[3] = pack_bf16(b.z, b.w);
    *(short8*)(out + (size_t)gid * 512 + lane * 8) = o.v;
}

// ---------------------------------------------------------------------------
// A (x) one-shot f32->bf16 into fragment-lane order, ks-INNER gid mapping:
// the 8 consecutive blocks sharing a 16-row group read it once (L2/L3-local).
// out[(ks*4096 + ms)*512 + lane*8 + j]
// ---------------------------------------------------------------------------
__global__ __launch_bounds__(256) void convert_frag_A(
    const float* __restrict__ src, unsigned short* __restrict__ out)
{
    int gid = blockIdx.x * 4 + (threadIdx.x >> 6);   // 0..131071
    int lane = threadIdx.x & 63;
    int ms = gid >> 5, ks = gid & 31;
    const float* p = src + (size_t)(ms * 16 + (lane & 15)) * 1024
                         + ks * 32 + (lane >> 4) * 8;
    f32x4 a = *(const f32x4*)p;
    f32x4 b = *(const f32x4*)(p + 4);
    union { uint32_t d[4]; short8 v; } o;
    o.d[0] = pack_bf16(a.x, a.y); o.d[1] = pack_bf16(a.z, a.w);
    o.d[2] = pack_bf16(b.x, b.y); o.d[3] = pack_bf16(b.z, b.w);
    *(short8*)(out + ((size_t)ks * 4096 + ms) * 512 + lane * 8) = o.v;
}

// ---------------------------------------------------------------------------
// energy GEMM v7: 256x256 tile, 8 waves (2x4, wave tile 128x64), BK=32.
// 4-phase K-step (T3), triple-buffered LDS with 2-deep prefetch and counted
// vmcnt(4) that never drains in the main loop (T4), setprio around MFMA (T5).
// Per phase: {ds_reads ; gload_lds issue ; barrier ; lgkmcnt(0) ; 8 MFMA ;
// barrier}. Reads cross the first barrier in flight; per-wave lgkm waits
// stagger waves so LDS and MFMA overlap across waves.
// Grid 1024 = 256 M-blocks x 4 N-blocks, XCD-swizzled.
// ---------------------------------------------------------------------------
__global__ __launch_bounds__(512, 2) void energy_gemm_v7(
    const unsigned short* __restrict__ Ahi,  // [32 ks][4096 msub][512]
    const unsigned short* __restrict__ Bhi,  // [32 ks][64 nsub][512]
    const float* __restrict__ dec, const float* __restrict__ v,
    float* __restrict__ energy)
{
    // 96 KB: three buffers of [A: 16 subtiles | B: 16 subtiles] x 1 KB
    __shared__ unsigned short lds[49152];

    int bid = blockIdx.x;
    int lid = (bid & 7) * 128 + (bid >> 3);  // 4 N-blocks of an M-block -> same XCD
    int mblk = lid >> 2, nblk = lid & 3;
    int m0 = mblk * BM, n0 = nblk * BN;
    int b = m0 >> 11;                        // 2048 rows per batch

    int t = threadIdx.x, wid = t >> 6, lane = t & 63;
    int wm = wid >> 2, wn = wid & 3;         // 2 x 4 waves, wave tile 128 x 64
    int kg = lane >> 4, lr = lane & 15;

    f32x4 acc[8][4] = {};

    // per-wave staging: 4 of the 32 chunks per K-tile
    auto stage2 = [&](int t2, int sbase, int i0) {
        #pragma unroll
        for (int i = i0; i < i0 + 2; ++i) {
            int c = wid * 4 + i;
            const unsigned short* g = (c < 16)
                ? Ahi + ((size_t)t2 * 4096 + mblk * 16 + c) * 512
                : Bhi + ((size_t)t2 * 64 + nblk * 16 + (c - 16)) * 512;
            gload_lds16(g + lane * 8, &lds[sbase + c * 512]);
        }
    };

#define RD_A(buf, mi) (*(const short8*)&(buf)[(wm * 8 + (mi)) * 512 + lane * 8])
#define RD_B(buf, ni) (*(const short8*)&(buf)[8192 + (wn * 4 + (ni)) * 512 + lane * 8])
#define MFMA4(mi, AF) \
    acc[mi][0] = __builtin_amdgcn_mfma_f32_16x16x32_bf16(AF, bf0, acc[mi][0], 0, 0, 0); \
    acc[mi][1] = __builtin_amdgcn_mfma_f32_16x16x32_bf16(AF, bf1, acc[mi][1], 0, 0, 0); \
    acc[mi][2] = __builtin_amdgcn_mfma_f32_16x16x32_bf16(AF, bf2, acc[mi][2], 0, 0, 0); \
    acc[mi][3] = __builtin_amdgcn_mfma_f32_16x16x32_bf16(AF, bf3, acc[mi][3], 0, 0, 0);
#define BAR()   __builtin_amdgcn_s_barrier()
#define LGKM0() asm volatile("s_waitcnt lgkmcnt(0)" ::: "memory")
#define PRIO1() __builtin_amdgcn_s_setprio(1)
#define PRIO0() __builtin_amdgcn_s_setprio(0)

    // ---- prologue: stage tiles 0 (buf0) and 1 (buf1); wait tile 0 resident
    stage2(0, 0, 0);     stage2(0, 0, 2);
    stage2(1, 16384, 0); stage2(1, 16384, 2);
    asm volatile("s_waitcnt vmcnt(4)" ::: "memory");
    BAR();

    int cb = 0;
    for (int ks = 0; ks < 32; ++ks) {
        int sb = cb + 2; if (sb >= 3) sb -= 3;
        unsigned short* buf = &lds[cb * 16384];
        const int sbase = sb * 16384;
        const bool st = (ks < 30);

        // ---- phase 0: bf0..3 + af0,af1 ; stage 2 chunks of tile ks+2
        short8 bf0 = RD_B(buf, 0), bf1 = RD_B(buf, 1);
        short8 bf2 = RD_B(buf, 2), bf3 = RD_B(buf, 3);
        {
            short8 af0 = RD_A(buf, 0), af1 = RD_A(buf, 1);
            if (st) stage2(ks + 2, sbase, 0);
            BAR(); LGKM0(); PRIO1();
            MFMA4(0, af0); MFMA4(1, af1);
            PRIO0(); BAR();
        }
        // ---- phase 1
        {
            short8 af2 = RD_A(buf, 2), af3 = RD_A(buf, 3);
            if (st) stage2(ks + 2, sbase, 2);
            BAR(); LGKM0(); PRIO1();
            MFMA4(2, af2); MFMA4(3, af3);
            PRIO0(); BAR();
        }
        // ---- phase 2
        {
            short8 af4 = RD_A(buf, 4), af5 = RD_A(buf, 5);
            BAR(); LGKM0(); PRIO1();
            MFMA4(4, af4); MFMA4(5, af5);
            PRIO0(); BAR();
        }
        // ---- phase 3: counted vmcnt — retire tile ks+1's 4 loads, keep
        // tile ks+2's 4 in flight across the barrier (never drain to 0)
        {
            short8 af6 = RD_A(buf, 6), af7 = RD_A(buf, 7);
            BAR(); LGKM0(); PRIO1();
            MFMA4(6, af6); MFMA4(7, af7);
            PRIO0();
            if (st) asm volatile("s_waitcnt vmcnt(4)" ::: "memory");
            else    asm volatile("s_waitcnt vmcnt(0)" ::: "memory");
            BAR();
        }
        cb = cb + 1; if (cb >= 3) cb -= 3;
    }

    // ---- epilogue: energy[m] += sum_n tanh(enc + dec) * v
    float vv[4], dd[4];
    #pragma unroll
    for (int ni = 0; ni < 4; ++ni) {
        int d = n0 + wn * 64 + ni * 16 + lr;
        vv[ni] = v[d];
        dd[ni] = dec[(size_t)b * 1024 + d];
    }
    #pragma unroll
    for (int mi = 0; mi < 8; ++mi) {
        #pragma unroll
        for (int r = 0; r < 4; ++r) {
            float local = 0.f;
            #pragma unroll
            for (int ni = 0; ni < 4; ++ni)
                local += fast_tanh(acc[mi][ni][r] + dd[ni]) * vv[ni];
            local += __shfl_xor(local, 1);
            local += __shfl_xor(local, 2);
            local += __shfl_xor(local, 4);
            local += __shfl_xor(local, 8);
            if (lr == 0) {
                int m = m0 + wm * 128 + mi * 16 + kg * 4 + r;
                atomicAdd(&energy[m], local);
            }
        }
    }
}

// ---------------------------------------------------------------------------
// Masked softmax over S per batch row. One block per b.
// ---------------------------------------------------------------------------
__global__ __launch_bounds__(256) void softmax_kernel(
    const float* __restrict__ energy, const int* __restrict__ mask,
    float* __restrict__ attn)
{
    int b = blockIdx.x;
    int t = threadIdx.x;
    int wid = t >> 6, lane = t & 63;
    __shared__ float wmax[4], wsum[4];

    float vals[8];
    float mx = -INFINITY;
    #pragma unroll
    for (int j = 0; j < 8; ++j) {
        int s = t + j * 256;
        float e = energy[(size_t)b * S_LEN + s];
        if (mask[(size_t)b * S_LEN + s] == 0) e = NEG_INF_F;
        vals[j] = e;
        mx = fmaxf(mx, e);
    }
    #pragma unroll
    for (int m = 1; m < 64; m <<= 1) mx = fmaxf(mx, __shfl_xor(mx, m));
    if (lane == 0) wmax[wid] = mx;
    __syncthreads();
    mx = fmaxf(fmaxf(wmax[0], wmax[1]), fmaxf(wmax[2], wmax[3]));

    float sum = 0.f;
    #pragma unroll
    for (int j = 0; j < 8; ++j) { vals[j] = expf(vals[j] - mx); sum += vals[j]; }
    #pragma unroll
    for (int m = 1; m < 64; m <<= 1) sum += __shfl_xor(sum, m);
    if (lane == 0) wsum[wid] = sum;
    __syncthreads();
    sum = wsum[0] + wsum[1] + wsum[2] + wsum[3];
    float inv = 1.f / sum;
    #pragma unroll
    for (int j = 0; j < 8; ++j)
        attn[(size_t)b * S_LEN + t + j * 256] = vals[j] * inv;
}

// ---------------------------------------------------------------------------
// context[b,e] = sum_s attn[b,s] * x[b,s,e]. Grid (4 e-chunks, 32 b, 16 s-chunks).
// ---------------------------------------------------------------------------
__global__ __launch_bounds__(256) void context_kernel(
    const float* __restrict__ attn, const float* __restrict__ x,
    float* __restrict__ ctx)
{
    int ec = blockIdx.x, b = blockIdx.y, sc = blockIdx.z;
    int e = ec * 256 + threadIdx.x;
    const float* xp = x + ((size_t)b * S_LEN + sc * 128) * KDIM + e;
    const float* ap = attn + (size_t)b * S_LEN + sc * 128;
    float acc = 0.f;
    #pragma unroll 4
    for (int s = 0; s < 128; ++s) acc += ap[s] * xp[(size_t)s * KDIM];
    atomicAdd(&ctx[(size_t)b * KDIM + e], acc);
}

// ---------------------------------------------------------------------------
extern "C" void kernel_launch(void* const* d_in, const int* in_sizes, int n_in,
                              void* d_out, int out_size, void* d_ws, size_t ws_size,
                              hipStream_t stream) {
    const float* dh   = (const float*)d_in[0];  // [32,1024]
    const float* x    = (const float*)d_in[1];  // [32,2048,1024]
    const int*   mask = (const int*)d_in[2];    // [32,2048]
    const float* Wh   = (const float*)d_in[3];  // [1024,1024]
    const float* Ws   = (const float*)d_in[4];  // [1024,1024]
    const float* v    = (const float*)d_in[5];  // [1024]

    float* ctx  = (float*)d_out;                 // [32*1024]
    float* attn = (float*)d_out + 32 * 1024;     // [32*2048]

    unsigned short* Ahi = (unsigned short*)d_ws;   // 67108864 el (128 MB)
    unsigned short* Bhi = Ahi + 67108864ull;       // 1048576 el (2 MB)
    float* dec    = (float*)(Bhi + 1048576ull);    // 32768 f32
    float* energy = dec + 32768;                   // 65536 f32

    hipMemsetAsync(energy, 0, 65536 * sizeof(float), stream);
    hipMemsetAsync(ctx, 0, 32768 * sizeof(float), stream);

    dec_kernel<<<1024, 256, 0, stream>>>(dh, Ws, dec);
    convert_frag_B<<<512, 256, 0, stream>>>(Wh, Bhi);
    convert_frag_A<<<32768, 256, 0, stream>>>(x, Ahi);
    energy_gemm_v7<<<1024, 512, 0, stream>>>(Ahi, Bhi, dec, v, energy);
    softmax_kernel<<<NBATCH, 256, 0, stream>>>(energy, mask, attn);
    context_kernel<<<dim3(4, NBATCH, 16), 256, 0, stream>>>(attn, x, ctx);
}